// Round 19
// baseline (337.474 us; speedup 1.0000x reference)
//
#include <hip/hip_runtime.h>
#include <hip/hip_fp16.h>
#include <math.h>

typedef unsigned int u32;
typedef _Float16 f16x8 __attribute__((ext_vector_type(8)));
typedef float f32x4 __attribute__((ext_vector_type(4)));

// Tree: DEPTH=18, N=2^19-1. H=E=64, V=26. Same algebraic folds as before.
// Round 19: r18 = 239us flat (kC 115 but total unchanged -> kD/overheads
// dominate). Two fixes: (1) deep-level IN-WAVE FOLD only where ntile==1
// (kC L12..L8: 5 barrier-rounds -> 1 wave-0 chain; kD L7..L3 per-wave fold,
// L2..L0 wave-0 fold: 8 barriers -> 1). No redundant tiles (r14's mistake).
// (2) sTE2 rows padded to 33 words (kills the 16-way bank conflict on
// tag_e2 reads, 1.86M conflicts/dispatch).

// ws offsets (32-bit words)
#define OFF_H1C1   0
#define OFF_BIAS2  128
#define OFF_BIASS  384
#define OFF_M      640
#define OFF_TAGE2  4736
#define OFF_MEMO18 6400
#define OFF_M18P   8064      // u32[26*32]    packed memo18
#define OFF_TE2P   8896      // u32[26*32]    packed tag_e2
#define OFF_M17P   9728      // u32[17576*32] packed memo17
#define OFF_H2P    572160    // u32[17576*32] packed h2 table
#define OFF_C2P    1134592   // u32[17576*32] packed c2 table
#define OFF_L8     1697024   // u32[256*32]   level-8 handoff (kC -> kD)
#define OFF_TH     5891296   // f32[676*64]   tag-head vectors (A1 -> A2)

__device__ __forceinline__ float sigmf(float x){
  return __fdividef(1.0f, 1.0f + __expf(-x));
}
__device__ __forceinline__ float tanhfast(float x){
  float t = __expf(-2.0f * fabsf(x));
  float r = __fdividef(1.0f - t, 1.0f + t);
  return copysignf(r, x);
}
__device__ __forceinline__ u32 pk_rn(float a, float b){
  __half2 h = __floats2half2_rn(a, b);
  return __builtin_bit_cast(u32, h);
}
__device__ __forceinline__ float logsoftmax64w(float tag){
  float m = tag;
  #pragma unroll
  for (int s = 32; s >= 1; s >>= 1) m = fmaxf(m, __shfl_xor(m, s, 64));
  float ex = __expf(tag - m);
  float sum = ex;
  #pragma unroll
  for (int s = 32; s >= 1; s >>= 1) sum += __shfl_xor(sum, s, 64);
  return tag - m - __logf(sum);
}

__device__ __forceinline__ f32x4 mm(uint4 a, uint4 b, f32x4 c){
  return __builtin_amdgcn_mfma_f32_16x16x32_f16(
      __builtin_bit_cast(f16x8, a), __builtin_bit_cast(f16x8, b), c, 0, 0, 0);
}

// One gate chunk jt: (i,f,g,o) rows for j = jt*16 + hi*4 + q.
template<bool HH>
__device__ __forceinline__ void gateChunk(const uint4* fi, const uint4* fh,
    int l, int jt, uint4 b0, uint4 b1, uint4 h0, uint4 h1,
    const f32x4* bias4, int hi, f32x4 cprev, f32x4& cq, f32x4& hq)
{
  f32x4 ai = bias4[(jt     )*4 + hi];
  f32x4 af = bias4[(4 + jt )*4 + hi];
  f32x4 ag = bias4[(8 + jt )*4 + hi];
  f32x4 ao = bias4[(12 + jt)*4 + hi];
  ai = mm(fi[((jt     )*2    )*64 + l], b0, ai);
  ai = mm(fi[((jt     )*2 + 1)*64 + l], b1, ai);
  af = mm(fi[((4 + jt )*2    )*64 + l], b0, af);
  af = mm(fi[((4 + jt )*2 + 1)*64 + l], b1, af);
  ag = mm(fi[((8 + jt )*2    )*64 + l], b0, ag);
  ag = mm(fi[((8 + jt )*2 + 1)*64 + l], b1, ag);
  ao = mm(fi[((12 + jt)*2    )*64 + l], b0, ao);
  ao = mm(fi[((12 + jt)*2 + 1)*64 + l], b1, ao);
  if (HH){
    ai = mm(fh[((jt     )*2    )*64 + l], h0, ai);
    ai = mm(fh[((jt     )*2 + 1)*64 + l], h1, ai);
    af = mm(fh[((4 + jt )*2    )*64 + l], h0, af);
    af = mm(fh[((4 + jt )*2 + 1)*64 + l], h1, af);
    ag = mm(fh[((8 + jt )*2    )*64 + l], h0, ag);
    ag = mm(fh[((8 + jt )*2 + 1)*64 + l], h1, ag);
    ao = mm(fh[((12 + jt)*2    )*64 + l], h0, ao);
    ao = mm(fh[((12 + jt)*2 + 1)*64 + l], h1, ao);
  }
  #pragma unroll
  for (int q = 0; q < 4; q++){
    float i_ = sigmf(ai[q]);
    float f_ = sigmf(af[q]);
    float g_ = tanhfast(ag[q]);
    float o_ = sigmf(ao[q]);
    float c = f_*cprev[q] + i_*g_;
    cq[q] = c;
    hq[q] = o_*tanhfast(c);
  }
}

__device__ __forceinline__ void putScrH(u32* scr, int n, int hi, int sw,
                                        int jt, f32x4 hq){
  uint2 pr; pr.x = pk_rn(hq[0], hq[1]); pr.y = pk_rn(hq[2], hq[3]);
  *(uint2*)&scr[n*32 + ((jt*8 + hi*2) ^ sw)] = pr;
  __builtin_amdgcn_sched_barrier(0);
}
__device__ __forceinline__ void readScr(const u32* scr, int n, int hi, int sw,
                                        uint4& b0, uint4& b1){
  b0 = *(const uint4*)&scr[n*32 + ((hi*4) ^ sw)];
  b1 = *(const uint4*)&scr[n*32 + ((16 + hi*4) ^ sw)];
}
__device__ __forceinline__ void loadB(const u32* row, int hi, uint4& b0, uint4& b1){
  b0 = *(const uint4*)(row + hi*4);
  b1 = *(const uint4*)(row + 16 + hi*4);
}
// LDS node-row buffers: row r, word w stored at w ^ ((r&7)<<2)
__device__ __forceinline__ void storeRowL(u32* buf, int r, int hi, const f32x4* v){
  int sw = (r & 7) << 2;
  #pragma unroll
  for (int jt = 0; jt < 4; jt++){
    uint2 pr; pr.x = pk_rn(v[jt][0], v[jt][1]); pr.y = pk_rn(v[jt][2], v[jt][3]);
    *(uint2*)&buf[r*32 + ((jt*8 + hi*2) ^ sw)] = pr;
  }
}
__device__ __forceinline__ void loadRowL(const u32* buf, int r, int hi,
                                         uint4& b0, uint4& b1){
  int sw = (r & 7) << 2;
  b0 = *(const uint4*)&buf[r*32 + ((hi*4) ^ sw)];
  b1 = *(const uint4*)&buf[r*32 + ((16 + hi*4) ^ sw)];
}
// per-wave out-buffer (fold): row n, uint2 slot s stored at (s+n)&7
__device__ __forceinline__ void storeOut(u32* ob, int n, int hi, const f32x4* v){
  #pragma unroll
  for (int jt = 0; jt < 4; jt++){
    uint2 pr; pr.x = pk_rn(v[jt][0], v[jt][1]); pr.y = pk_rn(v[jt][2], v[jt][3]);
    int slot = 2*jt + (hi >> 1);
    *(uint2*)&ob[n*32 + (((slot + n) & 7) << 2) + ((hi & 1) << 1)] = pr;
  }
  __builtin_amdgcn_sched_barrier(0);
}
__device__ __forceinline__ void loadOut(const u32* ob, int n, int hi,
                                        uint4& b0, uint4& b1){
  b0 = *(const uint4*)&ob[n*32 + (((hi     + n) & 7) << 2)];
  b1 = *(const uint4*)&ob[n*32 + (((hi + 4 + n) & 7) << 2)];
}
__device__ __forceinline__ void applyM(const uint4* fM, int l, uint4 b0, uint4 b1,
                                       f32x4* tac){
  #pragma unroll
  for (int rt = 0; rt < 4; rt++){
    tac[rt] = mm(fM[(rt*2+0)*64 + l], b0, tac[rt]);
    tac[rt] = mm(fM[(rt*2+1)*64 + l], b1, tac[rt]);
  }
  __builtin_amdgcn_sched_barrier(0);
}
__device__ __forceinline__ void addPkV(const u32* row, int hi, f32x4* v){
  #pragma unroll
  for (int jt = 0; jt < 4; jt++){
    uint2 u = *(const uint2*)(row + jt*8 + hi*2);
    float2 a = __half22float2(__builtin_bit_cast(__half2, u.x));
    float2 b = __half22float2(__builtin_bit_cast(__half2, u.y));
    v[jt][0] += a.x; v[jt][1] += a.y; v[jt][2] += b.x; v[jt][3] += b.y;
  }
}
__device__ __forceinline__ void setPkV(const u32* row, int hi, f32x4* v){
  #pragma unroll
  for (int jt = 0; jt < 4; jt++){
    uint2 u = *(const uint2*)(row + jt*8 + hi*2);
    float2 a = __half22float2(__builtin_bit_cast(__half2, u.x));
    float2 b = __half22float2(__builtin_bit_cast(__half2, u.y));
    v[jt][0] = a.x; v[jt][1] = a.y; v[jt][2] = b.x; v[jt][3] = b.y;
  }
}
__device__ __forceinline__ void storePkV(u32* row, int hi, const f32x4* v){
  #pragma unroll
  for (int jt = 0; jt < 4; jt++){
    uint2 pr; pr.x = pk_rn(v[jt][0], v[jt][1]); pr.y = pk_rn(v[jt][2], v[jt][3]);
    *(uint2*)(row + jt*8 + hi*2) = pr;
  }
}
__device__ __forceinline__ void lsm16v(f32x4* v){
  float m = v[0][0];
  #pragma unroll
  for (int k = 1; k < 16; k++) m = fmaxf(m, v[k >> 2][k & 3]);
  m = fmaxf(m, __shfl_xor(m, 16, 64));
  m = fmaxf(m, __shfl_xor(m, 32, 64));
  float s = 0.f;
  #pragma unroll
  for (int k = 0; k < 16; k++) s += __expf(v[k >> 2][k & 3] - m);
  s = s + __shfl_xor(s, 16, 64);
  s = s + __shfl_xor(s, 32, 64);
  float lse = m + __logf(s);
  #pragma unroll
  for (int k = 0; k < 16; k++) v[k >> 2][k & 3] -= lse;
}

__device__ __forceinline__ void stageW(const float* W, u32* dst, int nt){
  for (int idx = threadIdx.x; idx < 8192; idx += nt){
    int p = idx & 3, ll = (idx >> 2) & 63, th = idx >> 8;
    int rt = th >> 1, kh = th & 1;
    int g = rt*16 + (ll & 15);
    int k0 = kh*32 + ((ll >> 4) << 3) + 2*p;
    dst[idx] = pk_rn(W[g*64 + k0], W[g*64 + k0 + 1]);
  }
}

// One fold tile: children from a row buffer (SRCROW: rows 2*(srcBase+nc))
// or from the wave outbuf. Output -> outbuf row n; optional external row /
// global row / root stores. te2 rows are 33-word padded.
template<bool SRCROW, bool ROOT>
__device__ __forceinline__ void foldTile(
    const u32* src, int srcBase, u32* ob, int cnt, int idBase,
    const int* __restrict__ ids, const u32* te2,
    u32* extBuf, int extRow, u32* gRow, float* rootOut,
    const uint4* fWih, const uint4* fWhh, const uint4* fM,
    const f32x4* b2v, const f32x4* bsv, const f32x4* c1v,
    u32* scr, int n, int hi, int l, int sw)
{
  const f32x4 tz = {0.f, 0.f, 0.f, 0.f};
  bool ok = n < cnt;
  int nc = ok ? n : cnt - 1;
  uint4 b0, b1, h0, h1;
  f32x4 c2q[4];
  if (SRCROW) loadRowL(src, 2*(srcBase + nc), hi, b0, b1);
  else        loadOut(src, 2*nc, hi, b0, b1);
  #pragma unroll
  for (int jt = 0; jt < 4; jt++){
    f32x4 hq;
    gateChunk<false>(fWih, fWhh, l, jt, b0, b1, b0, b1, b2v, hi,
                     c1v[jt*4 + hi], c2q[jt], hq);
    putScrH(scr, n, hi, sw, jt, hq);
  }
  readScr(scr, n, hi, sw, h0, h1);
  if (SRCROW) loadRowL(src, 2*(srcBase + nc) + 1, hi, b0, b1);
  else        loadOut(src, 2*nc + 1, hi, b0, b1);
  #pragma unroll
  for (int jt = 0; jt < 4; jt++){
    f32x4 hq, cq;
    gateChunk<true>(fWih, fWhh, l, jt, b0, b1, h0, h1, bsv, hi,
                    c2q[jt], cq, hq);
    putScrH(scr, n, hi, sw, jt, hq);
  }
  readScr(scr, n, hi, sw, h0, h1);
  f32x4 tac[4] = {tz, tz, tz, tz};
  applyM(fM, l, h0, h1, tac);
  addPkV(te2 + ids[idBase + nc]*33, hi, tac);
  lsm16v(tac);
  if (ROOT){
    if (n == 0){
      #pragma unroll
      for (int jt = 0; jt < 4; jt++)
        #pragma unroll
        for (int q = 0; q < 4; q++)
          rootOut[jt*16 + hi*4 + q] = tac[jt][q];
    }
    return;
  }
  if (ok){
    storeOut(ob, n, hi, tac);
    if (extBuf) storeRowL(extBuf, extRow + n, hi, tac);
    if (gRow)   storePkV(gRow + n*32, hi, tac);
  }
}

// ---------------- precompute kernel (1 block, fp32) ----------------
__global__ __launch_bounds__(256) void k_pre(
    const float* __restrict__ emb,
    const float* __restrict__ W_ih, const float* __restrict__ W_hh,
    const float* __restrict__ b_ih, const float* __restrict__ b_hh,
    const float* __restrict__ W_comb, const float* __restrict__ b_comb,
    const float* __restrict__ W_tag, const float* __restrict__ b_tag,
    const float* __restrict__ lstm_init,
    float* __restrict__ ws)
{
  __shared__ float sWt[4096];
  __shared__ float sWc[8192];
  __shared__ float sg[256];
  __shared__ float sh1[64];
  __shared__ float sceT[64*32];
  __shared__ float sM[4096];
  __shared__ float ste[26*64];
  __shared__ float sth[64];
  __shared__ float sM18[26*64];
  int t = threadIdx.x;
  u32* wsu = (u32*)ws;

  for (int idx = t; idx < 4096; idx += 256) sWt[idx] = W_tag[idx];
  for (int idx = t; idx < 8192; idx += 256) sWc[idx] = W_comb[idx];

  float bsum = b_ih[t] + b_hh[t];
  ws[OFF_BIASS + t] = bsum;
  {
    float acc = bsum;
    for (int k = 0; k < 64; k++) acc = fmaf(W_ih[t*64 + k], lstm_init[k], acc);
    sg[t] = acc;
  }
  __syncthreads();

  if (t < 64){
    float ii = sigmf(sg[t]);
    float gg = tanhfast(sg[128 + t]);
    float oo = sigmf(sg[192 + t]);
    float c = ii * gg;
    float h = oo * tanhfast(c);
    sh1[t] = h;
    ws[OFF_H1C1 + t] = h;
    ws[OFF_H1C1 + 64 + t] = c;
  }
  __syncthreads();

  {
    float acc = bsum;
    for (int k = 0; k < 64; k++) acc = fmaf(W_hh[t*64 + k], sh1[k], acc);
    ws[OFF_BIAS2 + t] = acc;
  }
  for (int idx = t; idx < 26*64; idx += 256){
    int jj = idx / 26, v = idx - jj*26;
    float acc = b_comb[jj];
    for (int e = 0; e < 64; e++) acc = fmaf(sWc[jj*128 + 64 + e], emb[v*64 + e], acc);
    sceT[jj*32 + v] = acc;
  }
  for (int idx = t; idx < 4096; idx += 256){
    int jj = idx >> 6, kk = idx & 63;
    float acc = 0.f;
    for (int m = 0; m < 64; m++) acc = fmaf(sWt[jj*64 + m], sWc[m*128 + kk], acc);
    sM[idx] = acc;
    ws[OFF_M + idx] = acc;
  }
  __syncthreads();
  for (int idx = t; idx < 26*64; idx += 256){
    int jj = idx / 26, v = idx - jj*26;
    float acc = b_tag[jj];
    for (int k = 0; k < 64; k++) acc = fmaf(sWt[jj*64 + k], sceT[k*32 + v], acc);
    ws[OFF_TAGE2 + v*64 + jj] = acc;
    ste[v*64 + jj] = acc;
  }
  if (t < 64){
    float acc = 0.f;
    for (int k = 0; k < 64; k++) acc = fmaf(sM[t*64 + k], sh1[k], acc);
    sth[t] = acc;
  }
  __syncthreads();
  {
    int w = t >> 6, j = t & 63;
    for (int v = w; v < 26; v += 4){
      float tag = sth[j] + ste[v*64 + j];
      float lp = logsoftmax64w(tag);
      ws[OFF_MEMO18 + v*64 + j] = lp;
      sM18[v*64 + j] = lp;
    }
  }
  __syncthreads();
  for (int idx = t; idx < 26*32; idx += 256){
    int v = idx >> 5, m = idx & 31;
    wsu[OFF_M18P + idx] = pk_rn(sM18[v*64 + 2*m], sM18[v*64 + 2*m + 1]);
    wsu[OFF_TE2P + idx] = pk_rn(ste[v*64 + 2*m],  ste[v*64 + 2*m + 1]);
  }
}

// ---- kA1: 676 pairs -> th = M @ h3(lid,rid), f32 ----
__global__ __launch_bounds__(512, 2) void kA1(
    const float* __restrict__ W_ih, const float* __restrict__ W_hh,
    float* __restrict__ ws)
{
  __shared__ u32  sWihF[8192];
  __shared__ u32  sWhhF[8192];
  __shared__ u32  sMFm[2048];
  __shared__ float sB2[256];
  __shared__ float sBS[256];
  __shared__ float sC1[64];
  __shared__ u32  sScr[4096];
  u32* wsu = (u32*)ws;

  stageW(W_ih, sWihF, 512);
  stageW(W_hh, sWhhF, 512);
  for (int idx = threadIdx.x; idx < 2048; idx += 512){
    int p = idx & 3, ll = (idx >> 2) & 63, th = idx >> 8;
    int rt = th >> 1, kh = th & 1;
    int g = rt*16 + (ll & 15);
    int k0 = kh*32 + ((ll >> 4) << 3) + 2*p;
    sMFm[idx] = pk_rn(ws[OFF_M + g*64 + k0], ws[OFF_M + g*64 + k0 + 1]);
  }
  for (int idx = threadIdx.x; idx < 256; idx += 512){
    sB2[idx] = ws[OFF_BIAS2 + idx];
    sBS[idx] = ws[OFF_BIASS + idx];
  }
  if (threadIdx.x < 64) sC1[threadIdx.x] = ws[OFF_H1C1 + 64 + threadIdx.x];
  __syncthreads();

  int wv = threadIdx.x >> 6, l = threadIdx.x & 63;
  int n = l & 15, hi = l >> 4;
  int tile = blockIdx.x*8 + wv;
  if (tile >= 43) return;
  u32* scr = sScr + wv*512;
  int sw = (n & 7) << 2;
  const f32x4 tz = {0.f, 0.f, 0.f, 0.f};
  const uint4* fWih = (const uint4*)sWihF;
  const uint4* fWhh = (const uint4*)sWhhF;
  const uint4* fM   = (const uint4*)sMFm;
  const f32x4* b2v  = (const f32x4*)sB2;
  const f32x4* bsv  = (const f32x4*)sBS;
  const f32x4* c1v  = (const f32x4*)sC1;

  int p = tile*16 + n; bool ok = p < 676; int pc = ok ? p : 675;
  int lid = pc / 26, rid = pc - lid*26;
  uint4 b0, b1, h0, h1;
  f32x4 c2q[4];
  loadB(wsu + OFF_M18P + lid*32, hi, b0, b1);
  #pragma unroll
  for (int jt = 0; jt < 4; jt++){
    f32x4 hq;
    gateChunk<false>(fWih, fWhh, l, jt, b0, b1, b0, b1, b2v, hi,
                     c1v[jt*4 + hi], c2q[jt], hq);
    putScrH(scr, n, hi, sw, jt, hq);
  }
  readScr(scr, n, hi, sw, h0, h1);
  loadB(wsu + OFF_M18P + rid*32, hi, b0, b1);
  #pragma unroll
  for (int jt = 0; jt < 4; jt++){
    f32x4 hq, cq;
    gateChunk<true>(fWih, fWhh, l, jt, b0, b1, h0, h1, bsv, hi,
                    c2q[jt], cq, hq);
    putScrH(scr, n, hi, sw, jt, hq);
  }
  readScr(scr, n, hi, sw, h0, h1);
  f32x4 tac[4] = {tz, tz, tz, tz};
  applyM(fM, l, h0, h1, tac);
  if (ok){
    #pragma unroll
    for (int jt = 0; jt < 4; jt++)
      #pragma unroll
      for (int q = 0; q < 4; q++)
        ws[OFF_TH + pc*64 + jt*16 + hi*4 + q] = tac[jt][q];
  }
}

// ---- kA2: 17576 keys: memo17 = lsm(th[p]+te2[iid]) fused with h2/c2 ----
__global__ __launch_bounds__(512, 2) void kA2(
    const float* __restrict__ W_ih, float* __restrict__ ws)
{
  __shared__ u32  sWihF[8192];
  __shared__ float sB2[256];
  __shared__ float sC1[64];
  __shared__ u32  sScr[4096];
  u32* wsu = (u32*)ws;

  stageW(W_ih, sWihF, 512);
  for (int idx = threadIdx.x; idx < 256; idx += 512)
    sB2[idx] = ws[OFF_BIAS2 + idx];
  if (threadIdx.x < 64) sC1[threadIdx.x] = ws[OFF_H1C1 + 64 + threadIdx.x];
  __syncthreads();

  int wv = threadIdx.x >> 6, l = threadIdx.x & 63;
  int n = l & 15, hi = l >> 4;
  int tile = blockIdx.x*8 + wv;
  if (tile >= 1099) return;
  u32* scr = sScr + wv*512;
  int sw = (n & 7) << 2;
  const uint4* fWih = (const uint4*)sWihF;
  const f32x4* b2v  = (const f32x4*)sB2;
  const f32x4* c1v  = (const f32x4*)sC1;

  int key = tile*16 + n; bool ok = key < 17576; int kc = ok ? key : 17575;
  int p = kc / 26, iid = kc - p*26;

  f32x4 tv[4];
  #pragma unroll
  for (int jt = 0; jt < 4; jt++)
    #pragma unroll
    for (int q = 0; q < 4; q++){
      int j = jt*16 + hi*4 + q;
      tv[jt][q] = ws[OFF_TH + p*64 + j] + ws[OFF_TAGE2 + iid*64 + j];
    }
  lsm16v(tv);
  if (ok) storePkV(wsu + OFF_M17P + kc*32, hi, tv);
  #pragma unroll
  for (int jt = 0; jt < 4; jt++) putScrH(scr, n, hi, sw, jt, tv[jt]);
  uint4 b0, b1;
  readScr(scr, n, hi, sw, b0, b1);
  #pragma unroll
  for (int jt = 0; jt < 4; jt++){
    f32x4 hq, cq;
    gateChunk<false>(fWih, fWih, l, jt, b0, b1, b0, b1, b2v, hi,
                     c1v[jt*4 + hi], cq, hq);
    if (ok){
      uint2 ph; ph.x = pk_rn(hq[0], hq[1]); ph.y = pk_rn(hq[2], hq[3]);
      uint2 pc2; pc2.x = pk_rn(cq[0], cq[1]); pc2.y = pk_rn(cq[2], cq[3]);
      *(uint2*)&wsu[OFF_H2P + kc*32 + jt*8 + hi*2] = ph;
      *(uint2*)&wsu[OFF_C2P + kc*32 + jt*8 + hi*2] = pc2;
    }
    __builtin_amdgcn_sched_barrier(0);
  }
}

// ---- kC: levels 16..13 (rounds) + fold 12..8 (wave 0); LDS-resident ----
template<int NW>
__global__ __launch_bounds__(NW*64, 1) void kC(
    const int* __restrict__ ids,
    const float* __restrict__ W_ih, const float* __restrict__ W_hh,
    float* __restrict__ ws)
{
  __shared__ u32  sWihF[8192];   // 32 KB
  __shared__ u32  sWhhF[8192];   // 32 KB
  __shared__ u32  sMFm[2048];    //  8 KB
  __shared__ float sB2[256];
  __shared__ float sBS[256];
  __shared__ float sC1[64];
  __shared__ u32  sTE2[858];     // 26x33 padded packed tag_e2
  __shared__ u32  sScr[NW*512];  // NW*2 KB
  __shared__ u32  bufA[8192];    // 32 KB even-level rows (also fold outbuf)
  __shared__ u32  bufB[4096];    // 16 KB odd-level rows
  u32* wsu = (u32*)ws;
  const int NT = NW*64;

  stageW(W_ih, sWihF, NT);
  stageW(W_hh, sWhhF, NT);
  for (int idx = threadIdx.x; idx < 2048; idx += NT){
    int p = idx & 3, ll = (idx >> 2) & 63, th = idx >> 8;
    int rt = th >> 1, kh = th & 1;
    int g = rt*16 + (ll & 15);
    int k0 = kh*32 + ((ll >> 4) << 3) + 2*p;
    sMFm[idx] = pk_rn(ws[OFF_M + g*64 + k0], ws[OFF_M + g*64 + k0 + 1]);
  }
  for (int idx = threadIdx.x; idx < 256; idx += NT){
    sB2[idx] = ws[OFF_BIAS2 + idx];
    sBS[idx] = ws[OFF_BIASS + idx];
  }
  for (int idx = threadIdx.x; idx < 832; idx += NT){
    int v = idx >> 5, m = idx & 31;
    sTE2[v*33 + m] = wsu[OFF_TE2P + idx];
  }
  if (threadIdx.x < 64) sC1[threadIdx.x] = ws[OFF_H1C1 + 64 + threadIdx.x];
  __syncthreads();

  int wv = threadIdx.x >> 6, l = threadIdx.x & 63;
  int n = l & 15, hi = l >> 4;
  u32* scr = sScr + wv*512;
  int sw = (n & 7) << 2;
  const f32x4 tz = {0.f, 0.f, 0.f, 0.f};
  const uint4* fWih = (const uint4*)sWihF;
  const uint4* fWhh = (const uint4*)sWhhF;
  const uint4* fM   = (const uint4*)sMFm;
  const f32x4* b2v  = (const f32x4*)sB2;
  const f32x4* bsv  = (const f32x4*)sBS;
  const f32x4* c1v  = (const f32x4*)sC1;
  int b = blockIdx.x;

  // level 16: 256 nodes/block = 16 tiles; output -> bufA (block-local rows)
  for (int t = wv; t < 16; t += NW){
    int ibl = t*16 + n;
    int i = b*256 + ibl;
    int m0 = 2*i, m1 = 2*i + 1;
    int kL = (ids[262143 + 2*m0]*26 + ids[262143 + 2*m0 + 1])*26 + ids[131071 + m0];
    int kR = (ids[262143 + 2*m1]*26 + ids[262143 + 2*m1 + 1])*26 + ids[131071 + m1];
    int idv = ids[65535 + i];
    uint4 b0, b1, h0, h1;
    f32x4 c2q[4];
    loadB(wsu + OFF_M17P + kR*32, hi, b0, b1);
    loadB(wsu + OFF_H2P + kL*32, hi, h0, h1);
    setPkV(wsu + OFF_C2P + kL*32, hi, c2q);
    #pragma unroll
    for (int jt = 0; jt < 4; jt++){
      f32x4 hq, cq;
      gateChunk<true>(fWih, fWhh, l, jt, b0, b1, h0, h1, bsv, hi,
                      c2q[jt], cq, hq);
      putScrH(scr, n, hi, sw, jt, hq);
    }
    readScr(scr, n, hi, sw, h0, h1);
    f32x4 tac[4] = {tz, tz, tz, tz};
    applyM(fM, l, h0, h1, tac);
    addPkV(sTE2 + idv*33, hi, tac);
    lsm16v(tac);
    storeRowL(bufA, ibl, hi, tac);
  }
  __syncthreads();

  // levels 15..13: parallel rounds (ntile = 8,4,2)
  for (int lev = 15; lev >= 13; --lev){
    int cnt = 1 << (lev - 8);
    int ntile = (cnt + 15) >> 4;
    const u32* prevb = ((lev + 1) & 1) ? bufB : bufA;
    u32* curb = (lev & 1) ? bufB : bufA;
    int B = 1 << lev;
    for (int t = wv; t < ntile; t += NW){
      int il = t*16 + n; bool ok = il < cnt; int ilc = ok ? il : cnt - 1;
      uint4 b0, b1, h0, h1;
      f32x4 c2q[4];
      loadRowL(prevb, 2*ilc, hi, b0, b1);
      #pragma unroll
      for (int jt = 0; jt < 4; jt++){
        f32x4 hq;
        gateChunk<false>(fWih, fWhh, l, jt, b0, b1, b0, b1, b2v, hi,
                         c1v[jt*4 + hi], c2q[jt], hq);
        putScrH(scr, n, hi, sw, jt, hq);
      }
      readScr(scr, n, hi, sw, h0, h1);
      loadRowL(prevb, 2*ilc + 1, hi, b0, b1);
      #pragma unroll
      for (int jt = 0; jt < 4; jt++){
        f32x4 hq, cq;
        gateChunk<true>(fWih, fWhh, l, jt, b0, b1, h0, h1, bsv, hi,
                        c2q[jt], cq, hq);
        putScrH(scr, n, hi, sw, jt, hq);
      }
      readScr(scr, n, hi, sw, h0, h1);
      f32x4 tac[4] = {tz, tz, tz, tz};
      applyM(fM, l, h0, h1, tac);
      addPkV(sTE2 + ids[(B - 1) + b*cnt + ilc]*33, hi, tac);
      lsm16v(tac);
      if (ok) storeRowL(curb, ilc, hi, tac);
    }
    __syncthreads();
  }

  // fold levels 12..8 in wave 0: no barriers, outbuf = bufA (L14 dead),
  // children of L12 from bufB (L13 rows 0..31); L8 -> global.
  if (wv == 0){
    u32* ob = bufA;
    foldTile<true , false>(bufB, 0, ob, 16, 4095 + b*16, ids, sTE2,
        nullptr, 0, nullptr, nullptr, fWih, fWhh, fM, b2v, bsv, c1v,
        scr, n, hi, l, sw);
    foldTile<false, false>(ob, 0, ob, 8, 2047 + b*8, ids, sTE2,
        nullptr, 0, nullptr, nullptr, fWih, fWhh, fM, b2v, bsv, c1v,
        scr, n, hi, l, sw);
    foldTile<false, false>(ob, 0, ob, 4, 1023 + b*4, ids, sTE2,
        nullptr, 0, nullptr, nullptr, fWih, fWhh, fM, b2v, bsv, c1v,
        scr, n, hi, l, sw);
    foldTile<false, false>(ob, 0, ob, 2, 511 + b*2, ids, sTE2,
        nullptr, 0, nullptr, nullptr, fWih, fWhh, fM, b2v, bsv, c1v,
        scr, n, hi, l, sw);
    foldTile<false, false>(ob, 0, ob, 1, 255 + b, ids, sTE2,
        nullptr, 0, wsu + OFF_L8 + b*32, nullptr, fWih, fWhh, fM,
        b2v, bsv, c1v, scr, n, hi, l, sw);
  }
}

// ---- kD: tail levels 7..0 via folds; 1 block, 8 waves ----
__global__ __launch_bounds__(512, 2) void kD(
    const int* __restrict__ ids,
    const float* __restrict__ W_ih, const float* __restrict__ W_hh,
    float* __restrict__ ws, float* __restrict__ out)
{
  __shared__ u32  sWihF[8192];
  __shared__ u32  sWhhF[8192];
  __shared__ u32  sMFm[2048];
  __shared__ float sB2[256];
  __shared__ float sBS[256];
  __shared__ float sC1[64];
  __shared__ u32  sTE2[858];
  __shared__ u32  sScr[4096];
  __shared__ u32  bufA[8192];    // L8 input rows (256)
  __shared__ u32  bufB[4096];    // 8 wave outbufs
  __shared__ u32  sL3[256];      // L3 rows (8)
  u32* wsu = (u32*)ws;

  stageW(W_ih, sWihF, 512);
  stageW(W_hh, sWhhF, 512);
  for (int idx = threadIdx.x; idx < 2048; idx += 512){
    int p = idx & 3, ll = (idx >> 2) & 63, th = idx >> 8;
    int rt = th >> 1, kh = th & 1;
    int g = rt*16 + (ll & 15);
    int k0 = kh*32 + ((ll >> 4) << 3) + 2*p;
    sMFm[idx] = pk_rn(ws[OFF_M + g*64 + k0], ws[OFF_M + g*64 + k0 + 1]);
  }
  for (int idx = threadIdx.x; idx < 256; idx += 512){
    sB2[idx] = ws[OFF_BIAS2 + idx];
    sBS[idx] = ws[OFF_BIASS + idx];
  }
  for (int idx = threadIdx.x; idx < 832; idx += 512){
    int v = idx >> 5, m = idx & 31;
    sTE2[v*33 + m] = wsu[OFF_TE2P + idx];
  }
  if (threadIdx.x < 64) sC1[threadIdx.x] = ws[OFF_H1C1 + 64 + threadIdx.x];
  // stage L8 (256 rows) into bufA with the row swizzle
  for (int idx = threadIdx.x; idx < 8192; idx += 512){
    int r = idx >> 5, w = idx & 31;
    bufA[r*32 + (w ^ ((r & 7) << 2))] = wsu[OFF_L8 + idx];
  }
  __syncthreads();

  int wv = threadIdx.x >> 6, l = threadIdx.x & 63;
  int n = l & 15, hi = l >> 4;
  u32* scr = sScr + wv*512;
  int sw = (n & 7) << 2;
  const uint4* fWih = (const uint4*)sWihF;
  const uint4* fWhh = (const uint4*)sWhhF;
  const uint4* fM   = (const uint4*)sMFm;
  const f32x4* b2v  = (const f32x4*)sB2;
  const f32x4* bsv  = (const f32x4*)sBS;
  const f32x4* c1v  = (const f32x4*)sC1;

  // round 1: each wave folds its L7 tile down to one L3 node (no barriers)
  {
    u32* ob = bufB + wv*512;
    foldTile<true , false>(bufA, wv*16, ob, 16, 127 + wv*16, ids, sTE2,
        nullptr, 0, nullptr, nullptr, fWih, fWhh, fM, b2v, bsv, c1v,
        scr, n, hi, l, sw);
    foldTile<false, false>(ob, 0, ob, 8, 63 + wv*8, ids, sTE2,
        nullptr, 0, nullptr, nullptr, fWih, fWhh, fM, b2v, bsv, c1v,
        scr, n, hi, l, sw);
    foldTile<false, false>(ob, 0, ob, 4, 31 + wv*4, ids, sTE2,
        nullptr, 0, nullptr, nullptr, fWih, fWhh, fM, b2v, bsv, c1v,
        scr, n, hi, l, sw);
    foldTile<false, false>(ob, 0, ob, 2, 15 + wv*2, ids, sTE2,
        nullptr, 0, nullptr, nullptr, fWih, fWhh, fM, b2v, bsv, c1v,
        scr, n, hi, l, sw);
    foldTile<false, false>(ob, 0, ob, 1, 7 + wv, ids, sTE2,
        sL3, wv, nullptr, nullptr, fWih, fWhh, fM, b2v, bsv, c1v,
        scr, n, hi, l, sw);
  }
  __syncthreads();

  // round 2: wave 0 folds L2 -> L1 -> root
  if (wv == 0){
    u32* ob = bufB;
    foldTile<true , false>(sL3, 0, ob, 4, 3, ids, sTE2,
        nullptr, 0, nullptr, nullptr, fWih, fWhh, fM, b2v, bsv, c1v,
        scr, n, hi, l, sw);
    foldTile<false, false>(ob, 0, ob, 2, 1, ids, sTE2,
        nullptr, 0, nullptr, nullptr, fWih, fWhh, fM, b2v, bsv, c1v,
        scr, n, hi, l, sw);
    foldTile<false, true >(ob, 0, ob, 1, 0, ids, sTE2,
        nullptr, 0, nullptr, out, fWih, fWhh, fM, b2v, bsv, c1v,
        scr, n, hi, l, sw);
  }
}

extern "C" void kernel_launch(void* const* d_in, const int* in_sizes, int n_in,
                              void* d_out, int out_size, void* d_ws, size_t ws_size,
                              hipStream_t stream)
{
  (void)in_sizes; (void)n_in; (void)out_size; (void)ws_size;
  const int*   ids    = (const int*)  d_in[0];
  const float* emb    = (const float*)d_in[1];
  const float* W_ih   = (const float*)d_in[2];
  const float* W_hh   = (const float*)d_in[3];
  const float* b_ih   = (const float*)d_in[4];
  const float* b_hh   = (const float*)d_in[5];
  const float* W_comb = (const float*)d_in[6];
  const float* b_comb = (const float*)d_in[7];
  const float* W_tag  = (const float*)d_in[8];
  const float* b_tag  = (const float*)d_in[9];
  const float* linit  = (const float*)d_in[10];
  float* ws  = (float*)d_ws;
  float* out = (float*)d_out;

  k_pre<<<1, 256, 0, stream>>>(emb, W_ih, W_hh, b_ih, b_hh,
                               W_comb, b_comb, W_tag, b_tag, linit, ws);
  kA1<<<6, 512, 0, stream>>>(W_ih, W_hh, ws);
  kA2<<<138, 512, 0, stream>>>(W_ih, ws);

  int maxb16 = 0;
  if (hipOccupancyMaxActiveBlocksPerMultiprocessor(&maxb16,
        (const void*)kC<16>, 1024, 0) != hipSuccess)
    maxb16 = 0;
  if (maxb16 >= 1)
    kC<16><<<256, 1024, 0, stream>>>(ids, W_ih, W_hh, ws);
  else
    kC<8><<<256, 512, 0, stream>>>(ids, W_ih, W_hh, ws);

  kD<<<1, 512, 0, stream>>>(ids, W_ih, W_hh, ws, out);
}

// Round 20
// 238.302 us; speedup vs baseline: 1.4162x; 1.4162x over previous
//
#include <hip/hip_runtime.h>
#include <hip/hip_fp16.h>
#include <math.h>

typedef unsigned int u32;
typedef _Float16 f16x8 __attribute__((ext_vector_type(8)));
typedef float f32x4 __attribute__((ext_vector_type(4)));

// Tree: DEPTH=18, N=2^19-1. H=E=64, V=26. Same algebraic folds as before.
// Round 20: revert to r18 structure (239us best; r19 fold regressed kD 3x).
// ONE change kept from r19: sTE2 rows padded to 33 words in kC/kD --
// kills the 16-way LDS bank conflict on tag_e2 epilogue reads
// (1.86M conflicts/dispatch in kC).

// ws offsets (32-bit words)
#define OFF_H1C1   0
#define OFF_BIAS2  128
#define OFF_BIASS  384
#define OFF_M      640
#define OFF_TAGE2  4736
#define OFF_MEMO18 6400
#define OFF_M18P   8064      // u32[26*32]    packed memo18
#define OFF_TE2P   8896      // u32[26*32]    packed tag_e2
#define OFF_M17P   9728      // u32[17576*32] packed memo17
#define OFF_H2P    572160    // u32[17576*32] packed h2 table
#define OFF_C2P    1134592   // u32[17576*32] packed c2 table
#define OFF_L8     1697024   // u32[256*32]   level-8 handoff (kC -> kD)
#define OFF_TH     5891296   // f32[676*64]   tag-head vectors (A1 -> A2)

__device__ __forceinline__ float sigmf(float x){
  return __fdividef(1.0f, 1.0f + __expf(-x));
}
__device__ __forceinline__ float tanhfast(float x){
  float t = __expf(-2.0f * fabsf(x));
  float r = __fdividef(1.0f - t, 1.0f + t);
  return copysignf(r, x);
}
__device__ __forceinline__ u32 pk_rn(float a, float b){
  __half2 h = __floats2half2_rn(a, b);
  return __builtin_bit_cast(u32, h);
}
__device__ __forceinline__ float logsoftmax64w(float tag){
  float m = tag;
  #pragma unroll
  for (int s = 32; s >= 1; s >>= 1) m = fmaxf(m, __shfl_xor(m, s, 64));
  float ex = __expf(tag - m);
  float sum = ex;
  #pragma unroll
  for (int s = 32; s >= 1; s >>= 1) sum += __shfl_xor(sum, s, 64);
  return tag - m - __logf(sum);
}

__device__ __forceinline__ f32x4 mm(uint4 a, uint4 b, f32x4 c){
  return __builtin_amdgcn_mfma_f32_16x16x32_f16(
      __builtin_bit_cast(f16x8, a), __builtin_bit_cast(f16x8, b), c, 0, 0, 0);
}

// One gate chunk jt: (i,f,g,o) rows for j = jt*16 + hi*4 + q.
template<bool HH>
__device__ __forceinline__ void gateChunk(const uint4* fi, const uint4* fh,
    int l, int jt, uint4 b0, uint4 b1, uint4 h0, uint4 h1,
    const f32x4* bias4, int hi, f32x4 cprev, f32x4& cq, f32x4& hq)
{
  f32x4 ai = bias4[(jt     )*4 + hi];
  f32x4 af = bias4[(4 + jt )*4 + hi];
  f32x4 ag = bias4[(8 + jt )*4 + hi];
  f32x4 ao = bias4[(12 + jt)*4 + hi];
  ai = mm(fi[((jt     )*2    )*64 + l], b0, ai);
  ai = mm(fi[((jt     )*2 + 1)*64 + l], b1, ai);
  af = mm(fi[((4 + jt )*2    )*64 + l], b0, af);
  af = mm(fi[((4 + jt )*2 + 1)*64 + l], b1, af);
  ag = mm(fi[((8 + jt )*2    )*64 + l], b0, ag);
  ag = mm(fi[((8 + jt )*2 + 1)*64 + l], b1, ag);
  ao = mm(fi[((12 + jt)*2    )*64 + l], b0, ao);
  ao = mm(fi[((12 + jt)*2 + 1)*64 + l], b1, ao);
  if (HH){
    ai = mm(fh[((jt     )*2    )*64 + l], h0, ai);
    ai = mm(fh[((jt     )*2 + 1)*64 + l], h1, ai);
    af = mm(fh[((4 + jt )*2    )*64 + l], h0, af);
    af = mm(fh[((4 + jt )*2 + 1)*64 + l], h1, af);
    ag = mm(fh[((8 + jt )*2    )*64 + l], h0, ag);
    ag = mm(fh[((8 + jt )*2 + 1)*64 + l], h1, ag);
    ao = mm(fh[((12 + jt)*2    )*64 + l], h0, ao);
    ao = mm(fh[((12 + jt)*2 + 1)*64 + l], h1, ao);
  }
  #pragma unroll
  for (int q = 0; q < 4; q++){
    float i_ = sigmf(ai[q]);
    float f_ = sigmf(af[q]);
    float g_ = tanhfast(ag[q]);
    float o_ = sigmf(ao[q]);
    float c = f_*cprev[q] + i_*g_;
    cq[q] = c;
    hq[q] = o_*tanhfast(c);
  }
}

__device__ __forceinline__ void putScrH(u32* scr, int n, int hi, int sw,
                                        int jt, f32x4 hq){
  uint2 pr; pr.x = pk_rn(hq[0], hq[1]); pr.y = pk_rn(hq[2], hq[3]);
  *(uint2*)&scr[n*32 + ((jt*8 + hi*2) ^ sw)] = pr;
  __builtin_amdgcn_sched_barrier(0);
}
__device__ __forceinline__ void readScr(const u32* scr, int n, int hi, int sw,
                                        uint4& b0, uint4& b1){
  b0 = *(const uint4*)&scr[n*32 + ((hi*4) ^ sw)];
  b1 = *(const uint4*)&scr[n*32 + ((16 + hi*4) ^ sw)];
}
__device__ __forceinline__ void loadB(const u32* row, int hi, uint4& b0, uint4& b1){
  b0 = *(const uint4*)(row + hi*4);
  b1 = *(const uint4*)(row + 16 + hi*4);
}
// LDS node-row buffers: row r, word w stored at w ^ ((r&7)<<2)
__device__ __forceinline__ void storeRowL(u32* buf, int r, int hi, const f32x4* v){
  int sw = (r & 7) << 2;
  #pragma unroll
  for (int jt = 0; jt < 4; jt++){
    uint2 pr; pr.x = pk_rn(v[jt][0], v[jt][1]); pr.y = pk_rn(v[jt][2], v[jt][3]);
    *(uint2*)&buf[r*32 + ((jt*8 + hi*2) ^ sw)] = pr;
  }
}
__device__ __forceinline__ void loadRowL(const u32* buf, int r, int hi,
                                         uint4& b0, uint4& b1){
  int sw = (r & 7) << 2;
  b0 = *(const uint4*)&buf[r*32 + ((hi*4) ^ sw)];
  b1 = *(const uint4*)&buf[r*32 + ((16 + hi*4) ^ sw)];
}
__device__ __forceinline__ void applyM(const uint4* fM, int l, uint4 b0, uint4 b1,
                                       f32x4* tac){
  #pragma unroll
  for (int rt = 0; rt < 4; rt++){
    tac[rt] = mm(fM[(rt*2+0)*64 + l], b0, tac[rt]);
    tac[rt] = mm(fM[(rt*2+1)*64 + l], b1, tac[rt]);
  }
  __builtin_amdgcn_sched_barrier(0);
}
// PAD-aware variants: row word-stride passed explicitly.
__device__ __forceinline__ void addPkVs(const u32* row, int hi, f32x4* v){
  #pragma unroll
  for (int jt = 0; jt < 4; jt++){
    u32 ux = row[jt*8 + hi*2];
    u32 uy = row[jt*8 + hi*2 + 1];
    float2 a = __half22float2(__builtin_bit_cast(__half2, ux));
    float2 b = __half22float2(__builtin_bit_cast(__half2, uy));
    v[jt][0] += a.x; v[jt][1] += a.y; v[jt][2] += b.x; v[jt][3] += b.y;
  }
}
__device__ __forceinline__ void addPkV(const u32* row, int hi, f32x4* v){
  #pragma unroll
  for (int jt = 0; jt < 4; jt++){
    uint2 u = *(const uint2*)(row + jt*8 + hi*2);
    float2 a = __half22float2(__builtin_bit_cast(__half2, u.x));
    float2 b = __half22float2(__builtin_bit_cast(__half2, u.y));
    v[jt][0] += a.x; v[jt][1] += a.y; v[jt][2] += b.x; v[jt][3] += b.y;
  }
}
__device__ __forceinline__ void setPkV(const u32* row, int hi, f32x4* v){
  #pragma unroll
  for (int jt = 0; jt < 4; jt++){
    uint2 u = *(const uint2*)(row + jt*8 + hi*2);
    float2 a = __half22float2(__builtin_bit_cast(__half2, u.x));
    float2 b = __half22float2(__builtin_bit_cast(__half2, u.y));
    v[jt][0] = a.x; v[jt][1] = a.y; v[jt][2] = b.x; v[jt][3] = b.y;
  }
}
__device__ __forceinline__ void storePkV(u32* row, int hi, const f32x4* v){
  #pragma unroll
  for (int jt = 0; jt < 4; jt++){
    uint2 pr; pr.x = pk_rn(v[jt][0], v[jt][1]); pr.y = pk_rn(v[jt][2], v[jt][3]);
    *(uint2*)(row + jt*8 + hi*2) = pr;
  }
}
__device__ __forceinline__ void lsm16v(f32x4* v){
  float m = v[0][0];
  #pragma unroll
  for (int k = 1; k < 16; k++) m = fmaxf(m, v[k >> 2][k & 3]);
  m = fmaxf(m, __shfl_xor(m, 16, 64));
  m = fmaxf(m, __shfl_xor(m, 32, 64));
  float s = 0.f;
  #pragma unroll
  for (int k = 0; k < 16; k++) s += __expf(v[k >> 2][k & 3] - m);
  s = s + __shfl_xor(s, 16, 64);
  s = s + __shfl_xor(s, 32, 64);
  float lse = m + __logf(s);
  #pragma unroll
  for (int k = 0; k < 16; k++) v[k >> 2][k & 3] -= lse;
}

__device__ __forceinline__ void stageW(const float* W, u32* dst, int nt){
  for (int idx = threadIdx.x; idx < 8192; idx += nt){
    int p = idx & 3, ll = (idx >> 2) & 63, th = idx >> 8;
    int rt = th >> 1, kh = th & 1;
    int g = rt*16 + (ll & 15);
    int k0 = kh*32 + ((ll >> 4) << 3) + 2*p;
    dst[idx] = pk_rn(W[g*64 + k0], W[g*64 + k0 + 1]);
  }
}

// ---------------- precompute kernel (1 block, fp32) ----------------
__global__ __launch_bounds__(256) void k_pre(
    const float* __restrict__ emb,
    const float* __restrict__ W_ih, const float* __restrict__ W_hh,
    const float* __restrict__ b_ih, const float* __restrict__ b_hh,
    const float* __restrict__ W_comb, const float* __restrict__ b_comb,
    const float* __restrict__ W_tag, const float* __restrict__ b_tag,
    const float* __restrict__ lstm_init,
    float* __restrict__ ws)
{
  __shared__ float sWt[4096];
  __shared__ float sWc[8192];
  __shared__ float sg[256];
  __shared__ float sh1[64];
  __shared__ float sceT[64*32];
  __shared__ float sM[4096];
  __shared__ float ste[26*64];
  __shared__ float sth[64];
  __shared__ float sM18[26*64];
  int t = threadIdx.x;
  u32* wsu = (u32*)ws;

  for (int idx = t; idx < 4096; idx += 256) sWt[idx] = W_tag[idx];
  for (int idx = t; idx < 8192; idx += 256) sWc[idx] = W_comb[idx];

  float bsum = b_ih[t] + b_hh[t];
  ws[OFF_BIASS + t] = bsum;
  {
    float acc = bsum;
    for (int k = 0; k < 64; k++) acc = fmaf(W_ih[t*64 + k], lstm_init[k], acc);
    sg[t] = acc;
  }
  __syncthreads();

  if (t < 64){
    float ii = sigmf(sg[t]);
    float gg = tanhfast(sg[128 + t]);
    float oo = sigmf(sg[192 + t]);
    float c = ii * gg;
    float h = oo * tanhfast(c);
    sh1[t] = h;
    ws[OFF_H1C1 + t] = h;
    ws[OFF_H1C1 + 64 + t] = c;
  }
  __syncthreads();

  {
    float acc = bsum;
    for (int k = 0; k < 64; k++) acc = fmaf(W_hh[t*64 + k], sh1[k], acc);
    ws[OFF_BIAS2 + t] = acc;
  }
  for (int idx = t; idx < 26*64; idx += 256){
    int jj = idx / 26, v = idx - jj*26;
    float acc = b_comb[jj];
    for (int e = 0; e < 64; e++) acc = fmaf(sWc[jj*128 + 64 + e], emb[v*64 + e], acc);
    sceT[jj*32 + v] = acc;
  }
  for (int idx = t; idx < 4096; idx += 256){
    int jj = idx >> 6, kk = idx & 63;
    float acc = 0.f;
    for (int m = 0; m < 64; m++) acc = fmaf(sWt[jj*64 + m], sWc[m*128 + kk], acc);
    sM[idx] = acc;
    ws[OFF_M + idx] = acc;
  }
  __syncthreads();
  for (int idx = t; idx < 26*64; idx += 256){
    int jj = idx / 26, v = idx - jj*26;
    float acc = b_tag[jj];
    for (int k = 0; k < 64; k++) acc = fmaf(sWt[jj*64 + k], sceT[k*32 + v], acc);
    ws[OFF_TAGE2 + v*64 + jj] = acc;
    ste[v*64 + jj] = acc;
  }
  if (t < 64){
    float acc = 0.f;
    for (int k = 0; k < 64; k++) acc = fmaf(sM[t*64 + k], sh1[k], acc);
    sth[t] = acc;
  }
  __syncthreads();
  {
    int w = t >> 6, j = t & 63;
    for (int v = w; v < 26; v += 4){
      float tag = sth[j] + ste[v*64 + j];
      float lp = logsoftmax64w(tag);
      ws[OFF_MEMO18 + v*64 + j] = lp;
      sM18[v*64 + j] = lp;
    }
  }
  __syncthreads();
  for (int idx = t; idx < 26*32; idx += 256){
    int v = idx >> 5, m = idx & 31;
    wsu[OFF_M18P + idx] = pk_rn(sM18[v*64 + 2*m], sM18[v*64 + 2*m + 1]);
    wsu[OFF_TE2P + idx] = pk_rn(ste[v*64 + 2*m],  ste[v*64 + 2*m + 1]);
  }
}

// ---- kA1: 676 pairs -> th = M @ h3(lid,rid), f32 ----
__global__ __launch_bounds__(512, 2) void kA1(
    const float* __restrict__ W_ih, const float* __restrict__ W_hh,
    float* __restrict__ ws)
{
  __shared__ u32  sWihF[8192];
  __shared__ u32  sWhhF[8192];
  __shared__ u32  sMFm[2048];
  __shared__ float sB2[256];
  __shared__ float sBS[256];
  __shared__ float sC1[64];
  __shared__ u32  sScr[4096];
  u32* wsu = (u32*)ws;

  stageW(W_ih, sWihF, 512);
  stageW(W_hh, sWhhF, 512);
  for (int idx = threadIdx.x; idx < 2048; idx += 512){
    int p = idx & 3, ll = (idx >> 2) & 63, th = idx >> 8;
    int rt = th >> 1, kh = th & 1;
    int g = rt*16 + (ll & 15);
    int k0 = kh*32 + ((ll >> 4) << 3) + 2*p;
    sMFm[idx] = pk_rn(ws[OFF_M + g*64 + k0], ws[OFF_M + g*64 + k0 + 1]);
  }
  for (int idx = threadIdx.x; idx < 256; idx += 512){
    sB2[idx] = ws[OFF_BIAS2 + idx];
    sBS[idx] = ws[OFF_BIASS + idx];
  }
  if (threadIdx.x < 64) sC1[threadIdx.x] = ws[OFF_H1C1 + 64 + threadIdx.x];
  __syncthreads();

  int wv = threadIdx.x >> 6, l = threadIdx.x & 63;
  int n = l & 15, hi = l >> 4;
  int tile = blockIdx.x*8 + wv;
  if (tile >= 43) return;
  u32* scr = sScr + wv*512;
  int sw = (n & 7) << 2;
  const f32x4 tz = {0.f, 0.f, 0.f, 0.f};
  const uint4* fWih = (const uint4*)sWihF;
  const uint4* fWhh = (const uint4*)sWhhF;
  const uint4* fM   = (const uint4*)sMFm;
  const f32x4* b2v  = (const f32x4*)sB2;
  const f32x4* bsv  = (const f32x4*)sBS;
  const f32x4* c1v  = (const f32x4*)sC1;

  int p = tile*16 + n; bool ok = p < 676; int pc = ok ? p : 675;
  int lid = pc / 26, rid = pc - lid*26;
  uint4 b0, b1, h0, h1;
  f32x4 c2q[4];
  loadB(wsu + OFF_M18P + lid*32, hi, b0, b1);
  #pragma unroll
  for (int jt = 0; jt < 4; jt++){
    f32x4 hq;
    gateChunk<false>(fWih, fWhh, l, jt, b0, b1, b0, b1, b2v, hi,
                     c1v[jt*4 + hi], c2q[jt], hq);
    putScrH(scr, n, hi, sw, jt, hq);
  }
  readScr(scr, n, hi, sw, h0, h1);
  loadB(wsu + OFF_M18P + rid*32, hi, b0, b1);
  #pragma unroll
  for (int jt = 0; jt < 4; jt++){
    f32x4 hq, cq;
    gateChunk<true>(fWih, fWhh, l, jt, b0, b1, h0, h1, bsv, hi,
                    c2q[jt], cq, hq);
    putScrH(scr, n, hi, sw, jt, hq);
  }
  readScr(scr, n, hi, sw, h0, h1);
  f32x4 tac[4] = {tz, tz, tz, tz};
  applyM(fM, l, h0, h1, tac);
  if (ok){
    #pragma unroll
    for (int jt = 0; jt < 4; jt++)
      #pragma unroll
      for (int q = 0; q < 4; q++)
        ws[OFF_TH + pc*64 + jt*16 + hi*4 + q] = tac[jt][q];
  }
}

// ---- kA2: 17576 keys: memo17 = lsm(th[p]+te2[iid]) fused with h2/c2 ----
__global__ __launch_bounds__(512, 2) void kA2(
    const float* __restrict__ W_ih, float* __restrict__ ws)
{
  __shared__ u32  sWihF[8192];
  __shared__ float sB2[256];
  __shared__ float sC1[64];
  __shared__ u32  sScr[4096];
  u32* wsu = (u32*)ws;

  stageW(W_ih, sWihF, 512);
  for (int idx = threadIdx.x; idx < 256; idx += 512)
    sB2[idx] = ws[OFF_BIAS2 + idx];
  if (threadIdx.x < 64) sC1[threadIdx.x] = ws[OFF_H1C1 + 64 + threadIdx.x];
  __syncthreads();

  int wv = threadIdx.x >> 6, l = threadIdx.x & 63;
  int n = l & 15, hi = l >> 4;
  int tile = blockIdx.x*8 + wv;
  if (tile >= 1099) return;
  u32* scr = sScr + wv*512;
  int sw = (n & 7) << 2;
  const uint4* fWih = (const uint4*)sWihF;
  const f32x4* b2v  = (const f32x4*)sB2;
  const f32x4* c1v  = (const f32x4*)sC1;

  int key = tile*16 + n; bool ok = key < 17576; int kc = ok ? key : 17575;
  int p = kc / 26, iid = kc - p*26;

  f32x4 tv[4];
  #pragma unroll
  for (int jt = 0; jt < 4; jt++)
    #pragma unroll
    for (int q = 0; q < 4; q++){
      int j = jt*16 + hi*4 + q;
      tv[jt][q] = ws[OFF_TH + p*64 + j] + ws[OFF_TAGE2 + iid*64 + j];
    }
  lsm16v(tv);
  if (ok) storePkV(wsu + OFF_M17P + kc*32, hi, tv);
  #pragma unroll
  for (int jt = 0; jt < 4; jt++) putScrH(scr, n, hi, sw, jt, tv[jt]);
  uint4 b0, b1;
  readScr(scr, n, hi, sw, b0, b1);
  #pragma unroll
  for (int jt = 0; jt < 4; jt++){
    f32x4 hq, cq;
    gateChunk<false>(fWih, fWih, l, jt, b0, b1, b0, b1, b2v, hi,
                     c1v[jt*4 + hi], cq, hq);
    if (ok){
      uint2 ph; ph.x = pk_rn(hq[0], hq[1]); ph.y = pk_rn(hq[2], hq[3]);
      uint2 pc2; pc2.x = pk_rn(cq[0], cq[1]); pc2.y = pk_rn(cq[2], cq[3]);
      *(uint2*)&wsu[OFF_H2P + kc*32 + jt*8 + hi*2] = ph;
      *(uint2*)&wsu[OFF_C2P + kc*32 + jt*8 + hi*2] = pc2;
    }
    __builtin_amdgcn_sched_barrier(0);
  }
}

// ---- kC: levels 16..8 with LDS-resident inter-level buffers ----
template<int NW>
__global__ __launch_bounds__(NW*64, 1) void kC(
    const int* __restrict__ ids,
    const float* __restrict__ W_ih, const float* __restrict__ W_hh,
    float* __restrict__ ws)
{
  __shared__ u32  sWihF[8192];   // 32 KB
  __shared__ u32  sWhhF[8192];   // 32 KB
  __shared__ u32  sMFm[2048];    //  8 KB
  __shared__ float sB2[256];
  __shared__ float sBS[256];
  __shared__ float sC1[64];
  __shared__ u32  sTE2[858];     // 26x33-word padded packed tag_e2
  __shared__ u32  sScr[NW*512];  // NW*2 KB
  __shared__ u32  bufA[8192];    // 32 KB even-level rows
  __shared__ u32  bufB[4096];    // 16 KB odd-level rows
  u32* wsu = (u32*)ws;
  const int NT = NW*64;

  stageW(W_ih, sWihF, NT);
  stageW(W_hh, sWhhF, NT);
  for (int idx = threadIdx.x; idx < 2048; idx += NT){
    int p = idx & 3, ll = (idx >> 2) & 63, th = idx >> 8;
    int rt = th >> 1, kh = th & 1;
    int g = rt*16 + (ll & 15);
    int k0 = kh*32 + ((ll >> 4) << 3) + 2*p;
    sMFm[idx] = pk_rn(ws[OFF_M + g*64 + k0], ws[OFF_M + g*64 + k0 + 1]);
  }
  for (int idx = threadIdx.x; idx < 256; idx += NT){
    sB2[idx] = ws[OFF_BIAS2 + idx];
    sBS[idx] = ws[OFF_BIASS + idx];
  }
  for (int idx = threadIdx.x; idx < 832; idx += NT){
    int v = idx >> 5, m = idx & 31;
    sTE2[v*33 + m] = wsu[OFF_TE2P + idx];
  }
  if (threadIdx.x < 64) sC1[threadIdx.x] = ws[OFF_H1C1 + 64 + threadIdx.x];
  __syncthreads();

  int wv = threadIdx.x >> 6, l = threadIdx.x & 63;
  int n = l & 15, hi = l >> 4;
  u32* scr = sScr + wv*512;
  int sw = (n & 7) << 2;
  const f32x4 tz = {0.f, 0.f, 0.f, 0.f};
  const uint4* fWih = (const uint4*)sWihF;
  const uint4* fWhh = (const uint4*)sWhhF;
  const uint4* fM   = (const uint4*)sMFm;
  const f32x4* b2v  = (const f32x4*)sB2;
  const f32x4* bsv  = (const f32x4*)sBS;
  const f32x4* c1v  = (const f32x4*)sC1;
  int b = blockIdx.x;

  // level 16: 256 nodes/block = 16 tiles; output -> bufA (block-local rows)
  for (int t = wv; t < 16; t += NW){
    int ibl = t*16 + n;
    int i = b*256 + ibl;
    int m0 = 2*i, m1 = 2*i + 1;
    int kL = (ids[262143 + 2*m0]*26 + ids[262143 + 2*m0 + 1])*26 + ids[131071 + m0];
    int kR = (ids[262143 + 2*m1]*26 + ids[262143 + 2*m1 + 1])*26 + ids[131071 + m1];
    int idv = ids[65535 + i];
    uint4 b0, b1, h0, h1;
    f32x4 c2q[4];
    loadB(wsu + OFF_M17P + kR*32, hi, b0, b1);
    loadB(wsu + OFF_H2P + kL*32, hi, h0, h1);
    setPkV(wsu + OFF_C2P + kL*32, hi, c2q);
    #pragma unroll
    for (int jt = 0; jt < 4; jt++){
      f32x4 hq, cq;
      gateChunk<true>(fWih, fWhh, l, jt, b0, b1, h0, h1, bsv, hi,
                      c2q[jt], cq, hq);
      putScrH(scr, n, hi, sw, jt, hq);
    }
    readScr(scr, n, hi, sw, h0, h1);
    f32x4 tac[4] = {tz, tz, tz, tz};
    applyM(fM, l, h0, h1, tac);
    addPkVs(sTE2 + idv*33, hi, tac);
    lsm16v(tac);
    storeRowL(bufA, ibl, hi, tac);
  }
  __syncthreads();

  // levels 15..8, all LDS-resident; only the L8 row leaves to global
  for (int lev = 15; lev >= 8; --lev){
    int cnt = 1 << (lev - 8);
    int ntile = (cnt + 15) >> 4;
    const u32* prevb = ((lev + 1) & 1) ? bufB : bufA;
    u32* curb = (lev & 1) ? bufB : bufA;
    int B = 1 << lev;
    for (int t = wv; t < ntile; t += NW){
      int il = t*16 + n; bool ok = il < cnt; int ilc = ok ? il : cnt - 1;
      uint4 b0, b1, h0, h1;
      f32x4 c2q[4];
      loadRowL(prevb, 2*ilc, hi, b0, b1);
      #pragma unroll
      for (int jt = 0; jt < 4; jt++){
        f32x4 hq;
        gateChunk<false>(fWih, fWhh, l, jt, b0, b1, b0, b1, b2v, hi,
                         c1v[jt*4 + hi], c2q[jt], hq);
        putScrH(scr, n, hi, sw, jt, hq);
      }
      readScr(scr, n, hi, sw, h0, h1);
      loadRowL(prevb, 2*ilc + 1, hi, b0, b1);
      #pragma unroll
      for (int jt = 0; jt < 4; jt++){
        f32x4 hq, cq;
        gateChunk<true>(fWih, fWhh, l, jt, b0, b1, h0, h1, bsv, hi,
                        c2q[jt], cq, hq);
        putScrH(scr, n, hi, sw, jt, hq);
      }
      readScr(scr, n, hi, sw, h0, h1);
      f32x4 tac[4] = {tz, tz, tz, tz};
      applyM(fM, l, h0, h1, tac);
      addPkVs(sTE2 + ids[(B - 1) + b*cnt + ilc]*33, hi, tac);
      lsm16v(tac);
      if (ok){
        storeRowL(curb, ilc, hi, tac);
        if (lev == 8) storePkV(wsu + OFF_L8 + b*32, hi, tac);
      }
    }
    __syncthreads();
  }
}

// ---- kD: tail levels 7..0, 1 block, fully LDS-resident ----
__global__ __launch_bounds__(512, 2) void kD(
    const int* __restrict__ ids,
    const float* __restrict__ W_ih, const float* __restrict__ W_hh,
    float* __restrict__ ws, float* __restrict__ out)
{
  __shared__ u32  sWihF[8192];
  __shared__ u32  sWhhF[8192];
  __shared__ u32  sMFm[2048];
  __shared__ float sB2[256];
  __shared__ float sBS[256];
  __shared__ float sC1[64];
  __shared__ u32  sTE2[858];
  __shared__ u32  sScr[4096];
  __shared__ u32  bufA[8192];    // even levels (+ L8 input)
  __shared__ u32  bufB[4096];    // odd levels
  u32* wsu = (u32*)ws;

  stageW(W_ih, sWihF, 512);
  stageW(W_hh, sWhhF, 512);
  for (int idx = threadIdx.x; idx < 2048; idx += 512){
    int p = idx & 3, ll = (idx >> 2) & 63, th = idx >> 8;
    int rt = th >> 1, kh = th & 1;
    int g = rt*16 + (ll & 15);
    int k0 = kh*32 + ((ll >> 4) << 3) + 2*p;
    sMFm[idx] = pk_rn(ws[OFF_M + g*64 + k0], ws[OFF_M + g*64 + k0 + 1]);
  }
  for (int idx = threadIdx.x; idx < 256; idx += 512){
    sB2[idx] = ws[OFF_BIAS2 + idx];
    sBS[idx] = ws[OFF_BIASS + idx];
  }
  for (int idx = threadIdx.x; idx < 832; idx += 512){
    int v = idx >> 5, m = idx & 31;
    sTE2[v*33 + m] = wsu[OFF_TE2P + idx];
  }
  if (threadIdx.x < 64) sC1[threadIdx.x] = ws[OFF_H1C1 + 64 + threadIdx.x];
  // stage L8 (256 rows) from global into bufA with the row swizzle
  for (int idx = threadIdx.x; idx < 8192; idx += 512){
    int r = idx >> 5, w = idx & 31;
    bufA[r*32 + (w ^ ((r & 7) << 2))] = wsu[OFF_L8 + idx];
  }
  __syncthreads();

  int wv = threadIdx.x >> 6, l = threadIdx.x & 63;
  int n = l & 15, hi = l >> 4;
  u32* scr = sScr + wv*512;
  int sw = (n & 7) << 2;
  const f32x4 tz = {0.f, 0.f, 0.f, 0.f};
  const uint4* fWih = (const uint4*)sWihF;
  const uint4* fWhh = (const uint4*)sWhhF;
  const uint4* fM   = (const uint4*)sMFm;
  const f32x4* b2v  = (const f32x4*)sB2;
  const f32x4* bsv  = (const f32x4*)sBS;
  const f32x4* c1v  = (const f32x4*)sC1;

  for (int lev = 7; lev >= 0; --lev){
    int cnt = 1 << lev;
    int ntile = (cnt + 15) >> 4;
    const u32* prevb = ((lev + 1) & 1) ? bufB : bufA;
    u32* curb = (lev & 1) ? bufB : bufA;
    for (int t = wv; t < ntile; t += 8){
      int i0 = t*16 + n; bool ok = i0 < cnt; int i = ok ? i0 : cnt - 1;
      uint4 b0, b1, h0, h1;
      f32x4 c2q[4];
      loadRowL(prevb, 2*i, hi, b0, b1);
      #pragma unroll
      for (int jt = 0; jt < 4; jt++){
        f32x4 hq;
        gateChunk<false>(fWih, fWhh, l, jt, b0, b1, b0, b1, b2v, hi,
                         c1v[jt*4 + hi], c2q[jt], hq);
        putScrH(scr, n, hi, sw, jt, hq);
      }
      readScr(scr, n, hi, sw, h0, h1);
      loadRowL(prevb, 2*i + 1, hi, b0, b1);
      #pragma unroll
      for (int jt = 0; jt < 4; jt++){
        f32x4 hq, cq;
        gateChunk<true>(fWih, fWhh, l, jt, b0, b1, h0, h1, bsv, hi,
                        c2q[jt], cq, hq);
        putScrH(scr, n, hi, sw, jt, hq);
      }
      readScr(scr, n, hi, sw, h0, h1);
      f32x4 tac[4] = {tz, tz, tz, tz};
      applyM(fM, l, h0, h1, tac);
      addPkVs(sTE2 + ids[(cnt - 1) + i]*33, hi, tac);
      lsm16v(tac);
      if (lev == 0){
        if (n == 0){
          #pragma unroll
          for (int jt = 0; jt < 4; jt++)
            #pragma unroll
            for (int q = 0; q < 4; q++)
              out[jt*16 + hi*4 + q] = tac[jt][q];
        }
      } else if (ok){
        storeRowL(curb, i, hi, tac);
      }
    }
    __syncthreads();
  }
}

extern "C" void kernel_launch(void* const* d_in, const int* in_sizes, int n_in,
                              void* d_out, int out_size, void* d_ws, size_t ws_size,
                              hipStream_t stream)
{
  (void)in_sizes; (void)n_in; (void)out_size; (void)ws_size;
  const int*   ids    = (const int*)  d_in[0];
  const float* emb    = (const float*)d_in[1];
  const float* W_ih   = (const float*)d_in[2];
  const float* W_hh   = (const float*)d_in[3];
  const float* b_ih   = (const float*)d_in[4];
  const float* b_hh   = (const float*)d_in[5];
  const float* W_comb = (const float*)d_in[6];
  const float* b_comb = (const float*)d_in[7];
  const float* W_tag  = (const float*)d_in[8];
  const float* b_tag  = (const float*)d_in[9];
  const float* linit  = (const float*)d_in[10];
  float* ws  = (float*)d_ws;
  float* out = (float*)d_out;

  k_pre<<<1, 256, 0, stream>>>(emb, W_ih, W_hh, b_ih, b_hh,
                               W_comb, b_comb, W_tag, b_tag, linit, ws);
  kA1<<<6, 512, 0, stream>>>(W_ih, W_hh, ws);
  kA2<<<138, 512, 0, stream>>>(W_ih, ws);

  int maxb16 = 0;
  if (hipOccupancyMaxActiveBlocksPerMultiprocessor(&maxb16,
        (const void*)kC<16>, 1024, 0) != hipSuccess)
    maxb16 = 0;
  if (maxb16 >= 1)
    kC<16><<<256, 1024, 0, stream>>>(ids, W_ih, W_hh, ws);
  else
    kC<8><<<256, 512, 0, stream>>>(ids, W_ih, W_hh, ws);

  kD<<<1, 512, 0, stream>>>(ids, W_ih, W_hh, ws, out);
}